// Round 10
// baseline (785.270 us; speedup 1.0000x reference)
//
#include <hip/hip_runtime.h>
#include <hip/hip_bf16.h>
#include <math.h>

// Problem constants
#define Bz 4
#define Vz 2048
#define RA 40   // R*A = 5*8

typedef short bf16x8 __attribute__((ext_vector_type(8)));
typedef float f32x4 __attribute__((ext_vector_type(4)));

__device__ __forceinline__ unsigned fasu(float f){ union{float f;unsigned u;}x;x.f=f;return x.u; }
__device__ __forceinline__ float usaf(unsigned u){ union{unsigned u;float f;}x;x.u=u;return x.f; }

// fp32 -> bf16 RNE (weight split, done once per layer)
__device__ __forceinline__ unsigned short f2bf(float f) {
    unsigned u = fasu(f);
    unsigned r = u + 0x7FFF + ((u >> 16) & 1);
    return (unsigned short)(r >> 16);
}
__device__ __forceinline__ float bf2f(unsigned short h) { return usaf(((unsigned)h) << 16); }

__constant__ float NORM_MEAN_C[30] = {
    -3.7189561e-06f, 0.000286194f, 0.0020740835f, 6.5275993f, -0.0052857199f,
    10.554636f, 0.057773598f, 13.915789f, 0.060970016f, 16.840271f,
    0.0570364f, 19.415283f, 0.044104282f, 21.721455f, 0.11490919f,
    23.64683f, 0.099816084f, 25.365578f, 0.01769533f, 26.861437f,
    0.054662503f, 28.197876f, -0.0024771576f, 29.295244f, 0.039666731f,
    30.319246f, 0.0088442909f, 31.160933f, -0.026727753f, 31.874565f};
__constant__ float NORM_VAR_C[30] = {
    3.3091978e-06f, 0.00016750646f, 0.80988622f, 85135.219f, 1.5621265f,
    222580.2f, 8.812871f, 386912.78f, 10.180468f, 566622.44f,
    9.8600769f, 753158.06f, 7.8372045f, 942701.62f, 30.926426f,
    1117233.0f, 25.045353f, 1285543.9f, 6.3646226f, 1441639.1f,
    12.326629f, 1588653.4f, 6.9686499f, 1714707.9f, 10.755516f,
    1836677.8f, 8.416419f, 1940088.8f, 10.344138f, 2029969.6f};

__device__ __forceinline__ float elu_f(float x) {
    return x > 0.f ? x : expm1f(x);
}

// order-preserving float->uint map (uint max == float max, bit-exact)
__device__ __forceinline__ unsigned encf(float f) {
    unsigned u = fasu(f);
    return (f < 0.f) ? ~u : (u | 0x80000000u);
}
__device__ __forceinline__ float decf(unsigned u) {
    return (u & 0x80000000u) ? usaf(u & 0x7FFFFFFFu) : usaf(~u);
}

// Weight expand, parity-transformed: kb = ((r*CB + cblk)*4 + j)*2 + p,
// p=0 -> Ks[j]/2 = (K[r,j]+K[r,j+4])/2 ; p=1 -> Kd[j]/2 = (K[r,j]-K[r,j+4])/2.
// Split-bf16, fragment-linear within kb: off = (n>>4)*512 + (kk>>3)*128 +
// (n&15)*8 + (kk&7); lo plane at +T*32.
template <int CROW, int T, int KB>
__device__ __forceinline__ void expand_body(int e, const float* __restrict__ kern,
                                            unsigned short* __restrict__ wt) {
    constexpr int CB = (CROW == 128) ? 4 : 1;
    int kb = e / (T * 32);
    int rem = e % (T * 32);
    int n = rem >> 5, kk = rem & 31;
    int par = kb & 1;
    int jp = (kb >> 1) & 3;
    int g = kb >> 3;                 // = r*CB + cblk
    int cblk = g % CB;
    int r = g / CB;
    int c = cblk * 32 + kk;
    float v = 0.f;
    if (c < CROW) {
        float k1 = kern[((size_t)((r * 8 + jp) * T + n)) * CROW + c];
        float k2 = kern[((size_t)((r * 8 + jp + 4) * T + n)) * CROW + c];
        v = 0.5f * (par == 0 ? (k1 + k2) : (k1 - k2));
    }
    unsigned short hi = f2bf(v);
    unsigned short lo = f2bf(v - bf2f(hi));
    size_t off = ((size_t)kb * 2) * T * 32 + (n >> 4) * 512 + (kk >> 3) * 128 + (n & 15) * 8 + (kk & 7);
    wt[off] = hi;
    wt[off + (size_t)T * 32] = lo;
}

// One prep dispatch: norm + 3x expand + pool-buffer zero (region-dispatch).
__global__ void prep_k(const float* __restrict__ sig, float* __restrict__ x0,
                       const float* __restrict__ k0, unsigned short* __restrict__ wt0,
                       const float* __restrict__ k1, unsigned short* __restrict__ wt1,
                       const float* __restrict__ k2, unsigned short* __restrict__ wt2,
                       unsigned* __restrict__ gpool) {
    const int bid = blockIdx.x, tid = threadIdx.x;
    if (bid < 960) {
        int e = bid * 256 + tid;
        if (e < Bz * Vz * 30) {
            int c = e % 30;
            x0[e] = (sig[e] - NORM_MEAN_C[c]) * rsqrtf(NORM_VAR_C[c]);
        }
    } else if (bid < 1600) {
        int e = (bid - 960) * 256 + tid;
        if (e < 40 * 128 * 32) expand_body<30, 128, 40>(e, k0, wt0);
    } else if (bid < 4160) {
        int e = (bid - 1600) * 256 + tid;
        if (e < 160 * 128 * 32) expand_body<128, 128, 160>(e, k1, wt1);
    } else if (bid < 9280) {
        int e = (bid - 4160) * 256 + tid;
        if (e < 160 * 256 * 32) expand_body<128, 256, 160>(e, k2, wt2);
    } else {
        int e = (bid - 9280) * 256 + tid;
        if (e < Bz * 256) gpool[e] = 0u;
    }
}

// Fused conv GEMM, parity-decomposed angular correlation (R8) with MT m-tiles
// per wave (R9) and R10's register-lean inner loop. R9's MT=2 halved the B
// L2 stream (5.4->2.7GB) but spilled (acc=128 AGPR left 128 arch; 64 B-frag
// regs + 48 gather + 24 idx-save copies blew it -> 355MB scratch writes).
// R10: (a) nj-blocked B - one (bh,bl) pair (8 VGPR) live at a time, its 12
// MFMAs run immediately (230cy covers the next pair's L2 latency); A-frags
// (32 VGPR) loaded once per ap. (b) lean I-build ladder with 1-ap gather->use
// gap (930cy >= HBM 900): ap0 gatherA, ap1 interpA (frees 24), ap2 gatherB,
// ap3 interpB, ap4 idx/w prefetch AFTER last use (kills 24-reg save copies),
// ap5 butterfly, ap6/7 stores. ONE barrier per group.
// Epilogue: reconstruct out[o]=Se'+So', out[o+4]=Se'-So'; elu+bias; AMP
// argmax over 8 rotations; BN; write or fused global-max-pool (R6).
template <int CROW, int T, int KB, int NW, int MT, bool FUSE, bool POOL>
__global__ __launch_bounds__(64 * NW, 2) void conv_k(const float* __restrict__ x,
                                              const int* __restrict__ bc_idx,
                                              const float* __restrict__ bc_w,
                                              const unsigned short* __restrict__ wt,
                                              const float* __restrict__ bias,
                                              const float* __restrict__ g,
                                              const float* __restrict__ be,
                                              float* __restrict__ xout) {
    constexpr int CB = (CROW == 128) ? 4 : 1;   // c-blocks per r
    constexpr int G = KB / 8;                   // (r,cblk) groups
    constexpr int CW = 2 * NW / MT;             // threads per (v,jI) build unit
    constexpr int CPT = 32 / CW;                // c-elements per thread
    __shared__ unsigned short Ih[2][4096 * MT], Il[2][4096 * MT];
    __shared__ float normp[64 * MT][NW];
    __shared__ int bo[8 * MT];
    __shared__ unsigned poolmax[64 * NW];
    const int tid = threadIdx.x;
    const int wid = tid >> 6, lane = tid & 63;
    const int fr = lane & 15, fq = lane >> 4;
    const int fr2 = fr >> 2, om_l = fr & 3;
    const int wn = wid * 64;                      // column-wave offset
    const int m0 = blockIdx.y * (64 * MT);
    const int b = m0 >> 14;                       // batch
    const float* xb_ = x + (size_t)b * Vz * CROW;
    const int* idxb = bc_idx + (size_t)b * Vz * RA * 3;
    const float* wb = bc_w + (size_t)b * Vz * RA * 3;

    // I-build decomposition: thread = (vertex vbI, pair-index jI, c-chunk cidx)
    const int cidx = tid % CW;
    const int jI = (tid / CW) & 3;
    const int vbI = tid / (CW * 4);               // 0..8*MT-1
    const int vglob_b = ((m0 & 16383) >> 3) + vbI;
    const int wbase = vbI * 512 + ((cidx * CPT) >> 3) * 128 + ((cidx * CPT) & 7);
    const int nbase = wn >> 4;

    f32x4 acc[MT][4][4] = {};   // [mt][par*2+miq][nj]

    // pack split-bf16 and write to two slots (second optionally negated)
    auto store_split2 = [&](const float* vv, int buf, int sA, int sB, unsigned sgB) {
        unsigned hp[CPT / 2], lp[CPT / 2];
#pragma unroll
        for (int p2 = 0; p2 < CPT / 2; ++p2) {
            float v0 = vv[2 * p2], v1 = vv[2 * p2 + 1];
            unsigned u0 = fasu(v0), u1 = fasu(v1);
            unsigned h0 = u0 & 0xFFFF0000u, h1 = u1 & 0xFFFF0000u;
            float l0 = v0 - usaf(h0), l1 = v1 - usaf(h1);
            hp[p2] = (u0 >> 16) | h1;
            lp[p2] = (fasu(l0) >> 16) | (fasu(l1) & 0xFFFF0000u);
        }
        auto put = [&](int slot, unsigned sg) {
            const int sl = (slot & 8) | (((slot & 7) + 2 * (vbI & 3)) & 7);
            const int ad = wbase + sl * 8;
            if constexpr (CPT == 8) {
                *(uint4*)&Ih[buf][ad] = make_uint4(hp[0] ^ sg, hp[1] ^ sg, hp[2] ^ sg, hp[3] ^ sg);
                *(uint4*)&Il[buf][ad] = make_uint4(lp[0] ^ sg, lp[1] ^ sg, lp[2] ^ sg, lp[3] ^ sg);
            } else {
                *(uint2*)&Ih[buf][ad] = make_uint2(hp[0] ^ sg, hp[1] ^ sg);
                *(uint2*)&Il[buf][ad] = make_uint2(lp[0] ^ sg, lp[1] ^ sg);
            }
        };
        put(sA, 0u);
        put(sB, sgB);
    };

    // ---- prologue: build tile for group 0 (r=0,cblk=0); prefetch idx/w g=1 ----
    int i_n0 = 0, i_n1 = 0, i_n2 = 0, i_n3 = 0, i_n4 = 0, i_n5 = 0;
    float w_n0 = 0.f, w_n1 = 0.f, w_n2 = 0.f, w_n3 = 0.f, w_n4 = 0.f, w_n5 = 0.f;
    {
        const int gi1 = (vglob_b * RA + jI) * 3;
        const int gi2 = gi1 + 12;                 // (ra+4)*3
        int a0 = idxb[gi1], a1 = idxb[gi1 + 1], a2 = idxb[gi1 + 2];
        int a3 = idxb[gi2], a4 = idxb[gi2 + 1], a5 = idxb[gi2 + 2];
        float u0 = wb[gi1], u1 = wb[gi1 + 1], u2 = wb[gi1 + 2];
        float u3 = wb[gi2], u4 = wb[gi2 + 1], u5 = wb[gi2 + 2];
        float xj[CPT], xj4[CPT];
        const int cs0 = cidx * CPT;
        if (CROW == 128) {
            const float4* p0 = (const float4*)(xb_ + (size_t)a0 * CROW + cs0);
            const float4* p1 = (const float4*)(xb_ + (size_t)a1 * CROW + cs0);
            const float4* p2 = (const float4*)(xb_ + (size_t)a2 * CROW + cs0);
            const float4* p3 = (const float4*)(xb_ + (size_t)a3 * CROW + cs0);
            const float4* p4 = (const float4*)(xb_ + (size_t)a4 * CROW + cs0);
            const float4* p5 = (const float4*)(xb_ + (size_t)a5 * CROW + cs0);
#pragma unroll
            for (int qq = 0; qq < CPT / 4; ++qq) {
                float4 A = p0[qq], B = p1[qq], C = p2[qq];
                xj[qq * 4 + 0] = u0 * A.x + u1 * B.x + u2 * C.x;
                xj[qq * 4 + 1] = u0 * A.y + u1 * B.y + u2 * C.y;
                xj[qq * 4 + 2] = u0 * A.z + u1 * B.z + u2 * C.z;
                xj[qq * 4 + 3] = u0 * A.w + u1 * B.w + u2 * C.w;
                float4 D = p3[qq], E = p4[qq], F = p5[qq];
                xj4[qq * 4 + 0] = u3 * D.x + u4 * E.x + u5 * F.x;
                xj4[qq * 4 + 1] = u3 * D.y + u4 * E.y + u5 * F.y;
                xj4[qq * 4 + 2] = u3 * D.z + u4 * E.z + u5 * F.z;
                xj4[qq * 4 + 3] = u3 * D.w + u4 * E.w + u5 * F.w;
            }
        } else {
#pragma unroll
            for (int cc = 0; cc < CPT; ++cc) {
                int c = cs0 + cc;
                bool ok = (c < CROW);
                xj[cc] = ok ? (u0 * xb_[(size_t)a0 * CROW + c] + u1 * xb_[(size_t)a1 * CROW + c] + u2 * xb_[(size_t)a2 * CROW + c]) : 0.f;
                xj4[cc] = ok ? (u3 * xb_[(size_t)a3 * CROW + c] + u4 * xb_[(size_t)a4 * CROW + c] + u5 * xb_[(size_t)a5 * CROW + c]) : 0.f;
            }
        }
#pragma unroll
        for (int cc = 0; cc < CPT; ++cc) {
            float a_ = xj[cc], b_ = xj4[cc];
            xj[cc] = a_ + b_;                      // Ie
            xj4[cc] = a_ - b_;                     // Io
        }
        store_split2(xj, 0, jI, jI + 4, 0u);
        store_split2(xj4, 0, 8 + jI, 12 + jI, 0x80008000u);
        if (G > 1) {
            const int rn = 1 / CB;
            const int gi1n = (vglob_b * RA + rn * 8 + jI) * 3;
            const int gi2n = gi1n + 12;
            i_n0 = idxb[gi1n]; i_n1 = idxb[gi1n + 1]; i_n2 = idxb[gi1n + 2];
            i_n3 = idxb[gi2n]; i_n4 = idxb[gi2n + 1]; i_n5 = idxb[gi2n + 2];
            w_n0 = wb[gi1n]; w_n1 = wb[gi1n + 1]; w_n2 = wb[gi1n + 2];
            w_n3 = wb[gi2n]; w_n4 = wb[gi2n + 1]; w_n5 = wb[gi2n + 2];
        }
    }
    __syncthreads();

    for (int gidx = 0; gidx < G; ++gidx) {
        const bool hn = (gidx + 1 < G);
        const int cs_n = ((gidx + 1) % CB) * 32 + cidx * CPT;
        const int ibuf = gidx & 1;
        float4 qa0[CPT / 4], qa1[CPT / 4], qa2[CPT / 4];
        float4 qb0[CPT / 4], qb1[CPT / 4], qb2[CPT / 4];
        float sgA[3][CPT], sgB[3][CPT];            // CROW==30 scalar path
        float xj[CPT], xj4[CPT];
#pragma unroll
        for (int ap = 0; ap < 8; ++ap) {
            const int jp = ap >> 1, par = ap & 1;
            const int kb = gidx * 8 + ap;
            const unsigned short* bb = wt + ((size_t)kb * 2) * (T * 32) +
                                       (size_t)nbase * 512 + lane * 8;
            // ---- A fragments for all m-tiles (loaded once per ap) ----
            const int sp = (jp + om_l + 2 * fr2) & 7;   // slot low3 after swizzle
            const int sl = par * 8 + sp;
            bf16x8 ah[MT][2], al[MT][2];
#pragma unroll
            for (int mt = 0; mt < MT; ++mt)
#pragma unroll
                for (int miq = 0; miq < 2; ++miq) {
                    const int ad = mt * 4096 + (miq * 4 + fr2) * 512 + fq * 128 + sl * 8;
                    ah[mt][miq] = *(const bf16x8*)&Ih[ibuf][ad];
                    al[mt][miq] = *(const bf16x8*)&Il[ibuf][ad];
                }
            // ---- nj-blocked B: one (bh,bl) pair live; 12 MFMAs hide next load ----
#pragma unroll
            for (int nj = 0; nj < 4; ++nj) {
                bf16x8 bh = *(const bf16x8*)(bb + nj * 512);
                bf16x8 bl = *(const bf16x8*)(bb + (size_t)T * 32 + nj * 512);
                __builtin_amdgcn_s_setprio(1);
#pragma unroll
                for (int mt = 0; mt < MT; ++mt)
#pragma unroll
                    for (int miq = 0; miq < 2; ++miq) {
                        const int mi = par * 2 + miq;
                        acc[mt][mi][nj] = __builtin_amdgcn_mfma_f32_16x16x32_bf16(ah[mt][miq], bh, acc[mt][mi][nj], 0, 0, 0);
                        acc[mt][mi][nj] = __builtin_amdgcn_mfma_f32_16x16x32_bf16(ah[mt][miq], bl, acc[mt][mi][nj], 0, 0, 0);
                        acc[mt][mi][nj] = __builtin_amdgcn_mfma_f32_16x16x32_bf16(al[mt][miq], bh, acc[mt][mi][nj], 0, 0, 0);
                    }
                __builtin_amdgcn_s_setprio(0);
            }
            // ---- lean I-build ladder for group g+1 ----
            if (hn) {
                if (ap == 0) {
                    if (CROW == 128) {
                        const float4* p0 = (const float4*)(xb_ + (size_t)i_n0 * CROW + cs_n);
                        const float4* p1 = (const float4*)(xb_ + (size_t)i_n1 * CROW + cs_n);
                        const float4* p2 = (const float4*)(xb_ + (size_t)i_n2 * CROW + cs_n);
#pragma unroll
                        for (int qq = 0; qq < CPT / 4; ++qq) { qa0[qq] = p0[qq]; qa1[qq] = p1[qq]; qa2[qq] = p2[qq]; }
                    } else {
#pragma unroll
                        for (int cc = 0; cc < CPT; ++cc) {
                            int c = cs_n + cc;
                            bool ok = (c < CROW);
                            sgA[0][cc] = ok ? xb_[(size_t)i_n0 * CROW + c] : 0.f;
                            sgA[1][cc] = ok ? xb_[(size_t)i_n1 * CROW + c] : 0.f;
                            sgA[2][cc] = ok ? xb_[(size_t)i_n2 * CROW + c] : 0.f;
                        }
                    }
                } else if (ap == 1) {
                    if (CROW == 128) {
#pragma unroll
                        for (int qq = 0; qq < CPT / 4; ++qq) {
                            float4 A = qa0[qq], B = qa1[qq], C = qa2[qq];
                            xj[qq * 4 + 0] = w_n0 * A.x + w_n1 * B.x + w_n2 * C.x;
                            xj[qq * 4 + 1] = w_n0 * A.y + w_n1 * B.y + w_n2 * C.y;
                            xj[qq * 4 + 2] = w_n0 * A.z + w_n1 * B.z + w_n2 * C.z;
                            xj[qq * 4 + 3] = w_n0 * A.w + w_n1 * B.w + w_n2 * C.w;
                        }
                    } else {
#pragma unroll
                        for (int cc = 0; cc < CPT; ++cc)
                            xj[cc] = w_n0 * sgA[0][cc] + w_n1 * sgA[1][cc] + w_n2 * sgA[2][cc];
                    }
                } else if (ap == 2) {
                    if (CROW == 128) {
                        const float4* p3 = (const float4*)(xb_ + (size_t)i_n3 * CROW + cs_n);
                        const float4* p4 = (const float4*)(xb_ + (size_t)i_n4 * CROW + cs_n);
                        const float4* p5 = (const float4*)(xb_ + (size_t)i_n5 * CROW + cs_n);
#pragma unroll
                        for (int qq = 0; qq < CPT / 4; ++qq) { qb0[qq] = p3[qq]; qb1[qq] = p4[qq]; qb2[qq] = p5[qq]; }
                    } else {
#pragma unroll
                        for (int cc = 0; cc < CPT; ++cc) {
                            int c = cs_n + cc;
                            bool ok = (c < CROW);
                            sgB[0][cc] = ok ? xb_[(size_t)i_n3 * CROW + c] : 0.f;
                            sgB[1][cc] = ok ? xb_[(size_t)i_n4 * CROW + c] : 0.f;
                            sgB[2][cc] = ok ? xb_[(size_t)i_n5 * CROW + c] : 0.f;
                        }
                    }
                } else if (ap == 3) {
                    if (CROW == 128) {
#pragma unroll
                        for (int qq = 0; qq < CPT / 4; ++qq) {
                            float4 D = qb0[qq], E = qb1[qq], F = qb2[qq];
                            xj4[qq * 4 + 0] = w_n3 * D.x + w_n4 * E.x + w_n5 * F.x;
                            xj4[qq * 4 + 1] = w_n3 * D.y + w_n4 * E.y + w_n5 * F.y;
                            xj4[qq * 4 + 2] = w_n3 * D.z + w_n4 * E.z + w_n5 * F.z;
                            xj4[qq * 4 + 3] = w_n3 * D.w + w_n4 * E.w + w_n5 * F.w;
                        }
                    } else {
#pragma unroll
                        for (int cc = 0; cc < CPT; ++cc)
                            xj4[cc] = w_n3 * sgB[0][cc] + w_n4 * sgB[1][cc] + w_n5 * sgB[2][cc];
                    }
                } else if (ap == 4) {
                    // prefetch idx/w for group g+2 (after last use of w_n)
                    if (gidx + 2 < G) {
                        const int rn = (gidx + 2) / CB;
                        const int gi1 = (vglob_b * RA + rn * 8 + jI) * 3;
                        const int gi2 = gi1 + 12;
                        i_n0 = idxb[gi1]; i_n1 = idxb[gi1 + 1]; i_n2 = idxb[gi1 + 2];
                        i_n3 = idxb[gi2]; i_n4 = idxb[gi2 + 1]; i_n5 = idxb[gi2 + 2];
                        w_n0 = wb[gi1]; w_n1 = wb[gi1 + 1]; w_n2 = wb[gi1 + 2];
                        w_n3 = wb[gi2]; w_n4 = wb[gi2 + 1]; w_n5 = wb[gi2 + 2];
                    }
                } else if (ap == 5) {
#pragma unroll
                    for (int cc = 0; cc < CPT; ++cc) {
                        float a_ = xj[cc], b_ = xj4[cc];
                        xj[cc] = a_ + b_;          // Ie
                        xj4[cc] = a_ - b_;         // Io
                    }
                } else if (ap == 6) {
                    store_split2(xj, ibuf ^ 1, jI, jI + 4, 0u);
                } else {
                    store_split2(xj4, ibuf ^ 1, 8 + jI, 12 + jI, 0x80008000u);
                }
            }
        }
        __syncthreads();
    }

    if (FUSE) {
        // reconstruct out[o]=Se'+So', out[o+4]=Se'-So'; elu+bias; AMP; BN
        float ssP[MT][2][4], ssM[MT][2][4];
#pragma unroll
        for (int mt = 0; mt < MT; ++mt)
#pragma unroll
            for (int mg = 0; mg < 2; ++mg)
#pragma unroll
                for (int r = 0; r < 4; ++r) { ssP[mt][mg][r] = 0.f; ssM[mt][mg][r] = 0.f; }
#pragma unroll
        for (int mt = 0; mt < MT; ++mt)
#pragma unroll
            for (int mg = 0; mg < 2; ++mg)
#pragma unroll
                for (int nj = 0; nj < 4; ++nj)
#pragma unroll
                    for (int r = 0; r < 4; ++r) {
                        const int t = wn + nj * 16 + fr;
                        float se = acc[mt][mg][nj][r], so = acc[mt][mg + 2][nj][r];
                        float vP = elu_f(se + so + bias[t]);   // o = r
                        float vM = elu_f(se - so + bias[t]);   // o = r+4
                        acc[mt][mg][nj][r] = vP;
                        acc[mt][mg + 2][nj][r] = vM;
                        ssP[mt][mg][r] += vP * vP;
                        ssM[mt][mg][r] += vM * vM;
                    }
#pragma unroll
        for (int mt = 0; mt < MT; ++mt)
#pragma unroll
            for (int mg = 0; mg < 2; ++mg)
#pragma unroll
                for (int r = 0; r < 4; ++r) {
                    float s1 = ssP[mt][mg][r];
                    s1 += __shfl_xor(s1, 1); s1 += __shfl_xor(s1, 2);
                    s1 += __shfl_xor(s1, 4); s1 += __shfl_xor(s1, 8);
                    float s2 = ssM[mt][mg][r];
                    s2 += __shfl_xor(s2, 1); s2 += __shfl_xor(s2, 2);
                    s2 += __shfl_xor(s2, 4); s2 += __shfl_xor(s2, 8);
                    if (fr == 0) {
                        normp[(mt * 8 + mg * 4 + fq) * 8 + r][wid] = s1;
                        normp[(mt * 8 + mg * 4 + fq) * 8 + r + 4][wid] = s2;
                    }
                }
        __syncthreads();
        if (POOL) poolmax[tid] = 0u;
        if (tid < 8 * MT) {
            float best = -1.f; int bsel = 0;
#pragma unroll
            for (int oo = 0; oo < 8; ++oo) {
                float tot = 0.f;
#pragma unroll
                for (int wq = 0; wq < NW; ++wq) tot += normp[tid * 8 + oo][wq];
                if (tot > best) { best = tot; bsel = oo; }   // first max wins
            }
            bo[tid] = bsel;
        }
        __syncthreads();
        const float rsbn = rsqrtf(1.001f);
#pragma unroll
        for (int mt = 0; mt < MT; ++mt)
#pragma unroll
            for (int mg = 0; mg < 2; ++mg)
#pragma unroll
                for (int r = 0; r < 4; ++r) {
                    const int vloc = mt * 8 + mg * 4 + fq;
                    const int bsel = bo[vloc];
                    if (r == bsel) {
                        const int vg = (m0 >> 3) + vloc;
#pragma unroll
                        for (int nj = 0; nj < 4; ++nj) {
                            const int t = wn + nj * 16 + fr;
                            float f = acc[mt][mg][nj][r] * g[t] * rsbn + be[t];
                            if (!POOL) xout[(size_t)vg * T + t] = f;
                            else atomicMax(&poolmax[t], encf(f));
                        }
                    }
                    if (r + 4 == bsel) {
                        const int vg = (m0 >> 3) + vloc;
#pragma unroll
                        for (int nj = 0; nj < 4; ++nj) {
                            const int t = wn + nj * 16 + fr;
                            float f = acc[mt][mg + 2][nj][r] * g[t] * rsbn + be[t];
                            if (!POOL) xout[(size_t)vg * T + t] = f;
                            else atomicMax(&poolmax[t], encf(f));
                        }
                    }
                }
        if (POOL) {
            __syncthreads();
            unsigned pv = poolmax[tid];
            if (pv) atomicMax((unsigned*)xout + (((size_t)b) << 8) + tid, pv);
        }
    }
}

// Fused head: decode pooled max + 3-layer MLP. One block per batch.
__global__ __launch_bounds__(256) void head_k(const float* __restrict__ partial,
                                              const float* __restrict__ w1, const float* __restrict__ c1,
                                              const float* __restrict__ w2, const float* __restrict__ c2,
                                              const float* __restrict__ w3, const float* __restrict__ c3,
                                              float* __restrict__ outp) {
    __shared__ float p[256], h1s[512], h2s[256];
    const int b = blockIdx.x, tid = threadIdx.x;
    const unsigned* gp = (const unsigned*)partial;
    p[tid] = decf(gp[b * 256 + tid]);
    __syncthreads();
#pragma unroll
    for (int rep = 0; rep < 2; ++rep) {
        int n = rep * 256 + tid;
        float s = c1[n];
        for (int k = 0; k < 256; ++k) s += p[k] * w1[k * 512 + n];
        h1s[n] = elu_f(s);
    }
    __syncthreads();
    {
        float s = c2[tid];
        for (int k = 0; k < 512; ++k) s += h1s[k] * w2[k * 256 + tid];
        h2s[tid] = elu_f(s);
    }
    __syncthreads();
    if (tid < 40) {
        float s = c3[tid];
        for (int k = 0; k < 256; ++k) s += h2s[k] * w3[k * 40 + tid];
        outp[b * 40 + tid] = s;
    }
}

extern "C" void kernel_launch(void* const* d_in, const int* in_sizes, int n_in,
                              void* d_out, int out_size, void* d_ws, size_t ws_size,
                              hipStream_t stream) {
    const float* signal = (const float*)d_in[0];
    const int* bc_idx = (const int*)d_in[1];
    const float* bc_w = (const float*)d_in[2];
    const float* k0 = (const float*)d_in[3];
    const float* b0 = (const float*)d_in[4];
    const float* g0 = (const float*)d_in[5];
    const float* be0 = (const float*)d_in[6];
    const float* k1 = (const float*)d_in[7];
    const float* b1 = (const float*)d_in[8];
    const float* g1 = (const float*)d_in[9];
    const float* be1 = (const float*)d_in[10];
    const float* k2 = (const float*)d_in[11];
    const float* b2 = (const float*)d_in[12];
    const float* g2 = (const float*)d_in[13];
    const float* be2 = (const float*)d_in[14];
    const float* w1 = (const float*)d_in[15];
    const float* c1 = (const float*)d_in[16];
    const float* w2 = (const float*)d_in[17];
    const float* c2 = (const float*)d_in[18];
    const float* w3 = (const float*)d_in[19];
    const float* c3 = (const float*)d_in[20];
    float* outp = (float*)d_out;

    // Workspace layout: xa 4MB | xb 4MB | gpool 16KB | wt0 0.66MB | wt1 2.62MB | wt2 5.24MB
    float* ws = (float*)d_ws;
    float* xa = ws;                                        // [8192][<=128] f32
    float* xb = xa + (size_t)8192 * 128;
    unsigned* gpool = (unsigned*)(xb + (size_t)8192 * 128); // [4][256] enc-u32
    unsigned short* wt0 = (unsigned short*)(gpool + 4096);
    unsigned short* wt1 = wt0 + (size_t)40 * 2 * 128 * 32;
    unsigned short* wt2 = wt1 + (size_t)160 * 2 * 128 * 32;

    // 1. prep: norm -> xa, expand (parity-transformed) weights, zero gpool
    prep_k<<<9284, 256, 0, stream>>>(signal, xa, k0, wt0, k1, wt1, k2, wt2, gpool);

    // ---- layer 0: CROW=30 (KB=40), T=128, NW=2, MT=1, fused AMP ----
    conv_k<30, 128, 40, 2, 1, true, false><<<dim3(1, 1024), 128, 0, stream>>>(
        xa, bc_idx, bc_w, wt0, b0, g0, be0, xb);

    // ---- layer 1: CROW=128 (KB=160), T=128, NW=2, MT=1, fused AMP ----
    conv_k<128, 128, 160, 2, 1, true, false><<<dim3(1, 1024), 128, 0, stream>>>(
        xb, bc_idx, bc_w, wt1, b1, g1, be1, xa);

    // ---- layer 2: CROW=128 (KB=160), T=256, NW=4, MT=2 (BM=128), fused AMP+POOL ----
    conv_k<128, 256, 160, 4, 2, true, true><<<dim3(1, 512), 256, 0, stream>>>(
        xa, bc_idx, bc_w, wt2, b2, g2, be2, (float*)gpool);

    // ---- fused MLP head (decodes pooled max) ----
    head_k<<<Bz, 256, 0, stream>>>((const float*)gpool, w1, c1, w2, c2, w3, c3, outp);
}

// Round 11
// 763.906 us; speedup vs baseline: 1.0280x; 1.0280x over previous
//
#include <hip/hip_runtime.h>
#include <hip/hip_bf16.h>
#include <math.h>

// Problem constants
#define Bz 4
#define Vz 2048
#define RA 40   // R*A = 5*8

typedef short bf16x8 __attribute__((ext_vector_type(8)));
typedef float f32x4 __attribute__((ext_vector_type(4)));

__device__ __forceinline__ unsigned fasu(float f){ union{float f;unsigned u;}x;x.f=f;return x.u; }
__device__ __forceinline__ float usaf(unsigned u){ union{unsigned u;float f;}x;x.u=u;return x.f; }

// fp32 -> bf16 RNE (weight split, done once per layer)
__device__ __forceinline__ unsigned short f2bf(float f) {
    unsigned u = fasu(f);
    unsigned r = u + 0x7FFF + ((u >> 16) & 1);
    return (unsigned short)(r >> 16);
}
__device__ __forceinline__ float bf2f(unsigned short h) { return usaf(((unsigned)h) << 16); }

__constant__ float NORM_MEAN_C[30] = {
    -3.7189561e-06f, 0.000286194f, 0.0020740835f, 6.5275993f, -0.0052857199f,
    10.554636f, 0.057773598f, 13.915789f, 0.060970016f, 16.840271f,
    0.0570364f, 19.415283f, 0.044104282f, 21.721455f, 0.11490919f,
    23.64683f, 0.099816084f, 25.365578f, 0.01769533f, 26.861437f,
    0.054662503f, 28.197876f, -0.0024771576f, 29.295244f, 0.039666731f,
    30.319246f, 0.0088442909f, 31.160933f, -0.026727753f, 31.874565f};
__constant__ float NORM_VAR_C[30] = {
    3.3091978e-06f, 0.00016750646f, 0.80988622f, 85135.219f, 1.5621265f,
    222580.2f, 8.812871f, 386912.78f, 10.180468f, 566622.44f,
    9.8600769f, 753158.06f, 7.8372045f, 942701.62f, 30.926426f,
    1117233.0f, 25.045353f, 1285543.9f, 6.3646226f, 1441639.1f,
    12.326629f, 1588653.4f, 6.9686499f, 1714707.9f, 10.755516f,
    1836677.8f, 8.416419f, 1940088.8f, 10.344138f, 2029969.6f};

__device__ __forceinline__ float elu_f(float x) {
    return x > 0.f ? x : expm1f(x);
}

// order-preserving float->uint map (uint max == float max, bit-exact)
__device__ __forceinline__ unsigned encf(float f) {
    unsigned u = fasu(f);
    return (f < 0.f) ? ~u : (u | 0x80000000u);
}
__device__ __forceinline__ float decf(unsigned u) {
    return (u & 0x80000000u) ? usaf(u & 0x7FFFFFFFu) : usaf(~u);
}

// Weight expand, parity-transformed: kb = ((r*CB + cblk)*4 + j)*2 + p,
// p=0 -> Ks[j]/2 = (K[r,j]+K[r,j+4])/2 ; p=1 -> Kd[j]/2 = (K[r,j]-K[r,j+4])/2.
// Split-bf16, fragment-linear within kb: off = (n>>4)*512 + (kk>>3)*128 +
// (n&15)*8 + (kk&7); lo plane at +T*32.
template <int CROW, int T, int KB>
__device__ __forceinline__ void expand_body(int e, const float* __restrict__ kern,
                                            unsigned short* __restrict__ wt) {
    constexpr int CB = (CROW == 128) ? 4 : 1;
    int kb = e / (T * 32);
    int rem = e % (T * 32);
    int n = rem >> 5, kk = rem & 31;
    int par = kb & 1;
    int jp = (kb >> 1) & 3;
    int g = kb >> 3;                 // = r*CB + cblk
    int cblk = g % CB;
    int r = g / CB;
    int c = cblk * 32 + kk;
    float v = 0.f;
    if (c < CROW) {
        float k1 = kern[((size_t)((r * 8 + jp) * T + n)) * CROW + c];
        float k2 = kern[((size_t)((r * 8 + jp + 4) * T + n)) * CROW + c];
        v = 0.5f * (par == 0 ? (k1 + k2) : (k1 - k2));
    }
    unsigned short hi = f2bf(v);
    unsigned short lo = f2bf(v - bf2f(hi));
    size_t off = ((size_t)kb * 2) * T * 32 + (n >> 4) * 512 + (kk >> 3) * 128 + (n & 15) * 8 + (kk & 7);
    wt[off] = hi;
    wt[off + (size_t)T * 32] = lo;
}

// One prep dispatch: norm + 3x expand + pool-buffer zero (region-dispatch).
__global__ void prep_k(const float* __restrict__ sig, float* __restrict__ x0,
                       const float* __restrict__ k0, unsigned short* __restrict__ wt0,
                       const float* __restrict__ k1, unsigned short* __restrict__ wt1,
                       const float* __restrict__ k2, unsigned short* __restrict__ wt2,
                       unsigned* __restrict__ gpool) {
    const int bid = blockIdx.x, tid = threadIdx.x;
    if (bid < 960) {
        int e = bid * 256 + tid;
        if (e < Bz * Vz * 30) {
            int c = e % 30;
            x0[e] = (sig[e] - NORM_MEAN_C[c]) * rsqrtf(NORM_VAR_C[c]);
        }
    } else if (bid < 1600) {
        int e = (bid - 960) * 256 + tid;
        if (e < 40 * 128 * 32) expand_body<30, 128, 40>(e, k0, wt0);
    } else if (bid < 4160) {
        int e = (bid - 1600) * 256 + tid;
        if (e < 160 * 128 * 32) expand_body<128, 128, 160>(e, k1, wt1);
    } else if (bid < 9280) {
        int e = (bid - 4160) * 256 + tid;
        if (e < 160 * 256 * 32) expand_body<128, 256, 160>(e, k2, wt2);
    } else {
        int e = (bid - 9280) * 256 + tid;
        if (e < Bz * 256) gpool[e] = 0u;
    }
}

// Fused conv GEMM, parity-decomposed angular correlation (R8), MT m-tiles per
// block, NJF n-frags per wave (R11). R11: conv2 runs 8 waves x (128x32)
// wave-tiles (NW=8, MT=2, NJF=T/(16*NW)=2): block tile stays 128x256 so the
// B L2 stream is halved vs R8 (1024->512 slab sweeps, 5.4->2.7GB), but
// per-wave acc halves to 64 AGPR and I-build spreads over 64 units (CW=8,
// CPT=4) -> arch ~105 <= 128, NO spill (R9/R10's 355/142MB scratch was the
// 4-wave MT=2 failure). Cost: 1 block/CU (8 waves @ 2/SIMD) so no
// independent-block barrier overlap; B stream per SIMD also halves.
// conv0/conv1 instantiate NJF=4, bit-identical to the R10-verified path.
// Schedule per group: ap0 gatherA, ap1 interpA, ap2 gatherB, ap3 interpB,
// ap4 idx/w prefetch (after last use), ap5 butterfly, ap6/7 stores; B is
// nj-blocked (one (bh,bl) pair live, 12 MFMAs cover next load); ONE barrier
// per group. Epilogue: out[o]=Se'+So', out[o+4]=Se'-So'; elu+bias; AMP
// argmax over 8 rotations; BN; write or fused global-max-pool (R6).
template <int CROW, int T, int KB, int NW, int MT, bool FUSE, bool POOL>
__global__ __launch_bounds__(64 * NW, 2) void conv_k(const float* __restrict__ x,
                                              const int* __restrict__ bc_idx,
                                              const float* __restrict__ bc_w,
                                              const unsigned short* __restrict__ wt,
                                              const float* __restrict__ bias,
                                              const float* __restrict__ g,
                                              const float* __restrict__ be,
                                              float* __restrict__ xout) {
    constexpr int CB = (CROW == 128) ? 4 : 1;   // c-blocks per r
    constexpr int G = KB / 8;                   // (r,cblk) groups
    constexpr int CW = (64 * NW) / (8 * MT * 4);// threads per (v,jI) build unit
    constexpr int CPT = 32 / CW;                // c-elements per thread
    constexpr int NJF = T / (16 * NW);          // n-frags per wave
    __shared__ unsigned short Ih[2][4096 * MT], Il[2][4096 * MT];
    __shared__ float normp[64 * MT][NW];
    __shared__ int bo[8 * MT];
    __shared__ unsigned poolmax[T];
    const int tid = threadIdx.x;
    const int wid = tid >> 6, lane = tid & 63;
    const int fr = lane & 15, fq = lane >> 4;
    const int fr2 = fr >> 2, om_l = fr & 3;
    const int wn = wid * (16 * NJF);              // column-wave offset
    const int m0 = blockIdx.y * (64 * MT);
    const int b = m0 >> 14;                       // batch
    const float* xb_ = x + (size_t)b * Vz * CROW;
    const int* idxb = bc_idx + (size_t)b * Vz * RA * 3;
    const float* wb = bc_w + (size_t)b * Vz * RA * 3;

    // I-build decomposition: thread = (vertex vbI, pair-index jI, c-chunk cidx)
    const int cidx = tid % CW;
    const int jI = (tid / CW) & 3;
    const int vbI = tid / (CW * 4);               // 0..8*MT-1
    const int vglob_b = ((m0 & 16383) >> 3) + vbI;
    const int wbase = vbI * 512 + ((cidx * CPT) >> 3) * 128 + ((cidx * CPT) & 7);
    const int nbase = wn >> 4;

    f32x4 acc[MT][4][NJF] = {};   // [mt][par*2+miq][nj]

    // pack split-bf16 and write to two slots (second optionally negated)
    auto store_split2 = [&](const float* vv, int buf, int sA, int sB, unsigned sgB) {
        unsigned hp[CPT / 2], lp[CPT / 2];
#pragma unroll
        for (int p2 = 0; p2 < CPT / 2; ++p2) {
            float v0 = vv[2 * p2], v1 = vv[2 * p2 + 1];
            unsigned u0 = fasu(v0), u1 = fasu(v1);
            unsigned h0 = u0 & 0xFFFF0000u, h1 = u1 & 0xFFFF0000u;
            float l0 = v0 - usaf(h0), l1 = v1 - usaf(h1);
            hp[p2] = (u0 >> 16) | h1;
            lp[p2] = (fasu(l0) >> 16) | (fasu(l1) & 0xFFFF0000u);
        }
        auto put = [&](int slot, unsigned sg) {
            const int sl = (slot & 8) | (((slot & 7) + 2 * (vbI & 3)) & 7);
            const int ad = wbase + sl * 8;
            if constexpr (CPT == 8) {
                *(uint4*)&Ih[buf][ad] = make_uint4(hp[0] ^ sg, hp[1] ^ sg, hp[2] ^ sg, hp[3] ^ sg);
                *(uint4*)&Il[buf][ad] = make_uint4(lp[0] ^ sg, lp[1] ^ sg, lp[2] ^ sg, lp[3] ^ sg);
            } else {
                *(uint2*)&Ih[buf][ad] = make_uint2(hp[0] ^ sg, hp[1] ^ sg);
                *(uint2*)&Il[buf][ad] = make_uint2(lp[0] ^ sg, lp[1] ^ sg);
            }
        };
        put(sA, 0u);
        put(sB, sgB);
    };

    // ---- prologue: build tile for group 0 (r=0,cblk=0); prefetch idx/w g=1 ----
    int i_n0 = 0, i_n1 = 0, i_n2 = 0, i_n3 = 0, i_n4 = 0, i_n5 = 0;
    float w_n0 = 0.f, w_n1 = 0.f, w_n2 = 0.f, w_n3 = 0.f, w_n4 = 0.f, w_n5 = 0.f;
    {
        const int gi1 = (vglob_b * RA + jI) * 3;
        const int gi2 = gi1 + 12;                 // (ra+4)*3
        int a0 = idxb[gi1], a1 = idxb[gi1 + 1], a2 = idxb[gi1 + 2];
        int a3 = idxb[gi2], a4 = idxb[gi2 + 1], a5 = idxb[gi2 + 2];
        float u0 = wb[gi1], u1 = wb[gi1 + 1], u2 = wb[gi1 + 2];
        float u3 = wb[gi2], u4 = wb[gi2 + 1], u5 = wb[gi2 + 2];
        float xj[CPT], xj4[CPT];
        const int cs0 = cidx * CPT;
        if (CROW == 128) {
            const float4* p0 = (const float4*)(xb_ + (size_t)a0 * CROW + cs0);
            const float4* p1 = (const float4*)(xb_ + (size_t)a1 * CROW + cs0);
            const float4* p2 = (const float4*)(xb_ + (size_t)a2 * CROW + cs0);
            const float4* p3 = (const float4*)(xb_ + (size_t)a3 * CROW + cs0);
            const float4* p4 = (const float4*)(xb_ + (size_t)a4 * CROW + cs0);
            const float4* p5 = (const float4*)(xb_ + (size_t)a5 * CROW + cs0);
#pragma unroll
            for (int qq = 0; qq < CPT / 4; ++qq) {
                float4 A = p0[qq], B = p1[qq], C = p2[qq];
                xj[qq * 4 + 0] = u0 * A.x + u1 * B.x + u2 * C.x;
                xj[qq * 4 + 1] = u0 * A.y + u1 * B.y + u2 * C.y;
                xj[qq * 4 + 2] = u0 * A.z + u1 * B.z + u2 * C.z;
                xj[qq * 4 + 3] = u0 * A.w + u1 * B.w + u2 * C.w;
                float4 D = p3[qq], E = p4[qq], F = p5[qq];
                xj4[qq * 4 + 0] = u3 * D.x + u4 * E.x + u5 * F.x;
                xj4[qq * 4 + 1] = u3 * D.y + u4 * E.y + u5 * F.y;
                xj4[qq * 4 + 2] = u3 * D.z + u4 * E.z + u5 * F.z;
                xj4[qq * 4 + 3] = u3 * D.w + u4 * E.w + u5 * F.w;
            }
        } else {
#pragma unroll
            for (int cc = 0; cc < CPT; ++cc) {
                int c = cs0 + cc;
                bool ok = (c < CROW);
                xj[cc] = ok ? (u0 * xb_[(size_t)a0 * CROW + c] + u1 * xb_[(size_t)a1 * CROW + c] + u2 * xb_[(size_t)a2 * CROW + c]) : 0.f;
                xj4[cc] = ok ? (u3 * xb_[(size_t)a3 * CROW + c] + u4 * xb_[(size_t)a4 * CROW + c] + u5 * xb_[(size_t)a5 * CROW + c]) : 0.f;
            }
        }
#pragma unroll
        for (int cc = 0; cc < CPT; ++cc) {
            float a_ = xj[cc], b_ = xj4[cc];
            xj[cc] = a_ + b_;                      // Ie
            xj4[cc] = a_ - b_;                     // Io
        }
        store_split2(xj, 0, jI, jI + 4, 0u);
        store_split2(xj4, 0, 8 + jI, 12 + jI, 0x80008000u);
        if (G > 1) {
            const int rn = 1 / CB;
            const int gi1n = (vglob_b * RA + rn * 8 + jI) * 3;
            const int gi2n = gi1n + 12;
            i_n0 = idxb[gi1n]; i_n1 = idxb[gi1n + 1]; i_n2 = idxb[gi1n + 2];
            i_n3 = idxb[gi2n]; i_n4 = idxb[gi2n + 1]; i_n5 = idxb[gi2n + 2];
            w_n0 = wb[gi1n]; w_n1 = wb[gi1n + 1]; w_n2 = wb[gi1n + 2];
            w_n3 = wb[gi2n]; w_n4 = wb[gi2n + 1]; w_n5 = wb[gi2n + 2];
        }
    }
    __syncthreads();

    for (int gidx = 0; gidx < G; ++gidx) {
        const bool hn = (gidx + 1 < G);
        const int cs_n = ((gidx + 1) % CB) * 32 + cidx * CPT;
        const int ibuf = gidx & 1;
        float4 qa0[CPT / 4], qa1[CPT / 4], qa2[CPT / 4];
        float4 qb0[CPT / 4], qb1[CPT / 4], qb2[CPT / 4];
        float sgA[3][CPT], sgB[3][CPT];            // CROW==30 scalar path
        float xj[CPT], xj4[CPT];
#pragma unroll
        for (int ap = 0; ap < 8; ++ap) {
            const int jp = ap >> 1, par = ap & 1;
            const int kb = gidx * 8 + ap;
            const unsigned short* bb = wt + ((size_t)kb * 2) * (T * 32) +
                                       (size_t)nbase * 512 + lane * 8;
            // ---- A fragments for all m-tiles (loaded once per ap) ----
            const int sp = (jp + om_l + 2 * fr2) & 7;   // slot low3 after swizzle
            const int sl = par * 8 + sp;
            bf16x8 ah[MT][2], al[MT][2];
#pragma unroll
            for (int mt = 0; mt < MT; ++mt)
#pragma unroll
                for (int miq = 0; miq < 2; ++miq) {
                    const int ad = mt * 4096 + (miq * 4 + fr2) * 512 + fq * 128 + sl * 8;
                    ah[mt][miq] = *(const bf16x8*)&Ih[ibuf][ad];
                    al[mt][miq] = *(const bf16x8*)&Il[ibuf][ad];
                }
            // ---- nj-blocked B: one (bh,bl) pair live; MFMAs hide next load ----
#pragma unroll
            for (int nj = 0; nj < NJF; ++nj) {
                bf16x8 bh = *(const bf16x8*)(bb + nj * 512);
                bf16x8 bl = *(const bf16x8*)(bb + (size_t)T * 32 + nj * 512);
                __builtin_amdgcn_s_setprio(1);
#pragma unroll
                for (int mt = 0; mt < MT; ++mt)
#pragma unroll
                    for (int miq = 0; miq < 2; ++miq) {
                        const int mi = par * 2 + miq;
                        acc[mt][mi][nj] = __builtin_amdgcn_mfma_f32_16x16x32_bf16(ah[mt][miq], bh, acc[mt][mi][nj], 0, 0, 0);
                        acc[mt][mi][nj] = __builtin_amdgcn_mfma_f32_16x16x32_bf16(ah[mt][miq], bl, acc[mt][mi][nj], 0, 0, 0);
                        acc[mt][mi][nj] = __builtin_amdgcn_mfma_f32_16x16x32_bf16(al[mt][miq], bh, acc[mt][mi][nj], 0, 0, 0);
                    }
                __builtin_amdgcn_s_setprio(0);
            }
            // ---- lean I-build ladder for group g+1 ----
            if (hn) {
                if (ap == 0) {
                    if (CROW == 128) {
                        const float4* p0 = (const float4*)(xb_ + (size_t)i_n0 * CROW + cs_n);
                        const float4* p1 = (const float4*)(xb_ + (size_t)i_n1 * CROW + cs_n);
                        const float4* p2 = (const float4*)(xb_ + (size_t)i_n2 * CROW + cs_n);
#pragma unroll
                        for (int qq = 0; qq < CPT / 4; ++qq) { qa0[qq] = p0[qq]; qa1[qq] = p1[qq]; qa2[qq] = p2[qq]; }
                    } else {
#pragma unroll
                        for (int cc = 0; cc < CPT; ++cc) {
                            int c = cs_n + cc;
                            bool ok = (c < CROW);
                            sgA[0][cc] = ok ? xb_[(size_t)i_n0 * CROW + c] : 0.f;
                            sgA[1][cc] = ok ? xb_[(size_t)i_n1 * CROW + c] : 0.f;
                            sgA[2][cc] = ok ? xb_[(size_t)i_n2 * CROW + c] : 0.f;
                        }
                    }
                } else if (ap == 1) {
                    if (CROW == 128) {
#pragma unroll
                        for (int qq = 0; qq < CPT / 4; ++qq) {
                            float4 A = qa0[qq], B = qa1[qq], C = qa2[qq];
                            xj[qq * 4 + 0] = w_n0 * A.x + w_n1 * B.x + w_n2 * C.x;
                            xj[qq * 4 + 1] = w_n0 * A.y + w_n1 * B.y + w_n2 * C.y;
                            xj[qq * 4 + 2] = w_n0 * A.z + w_n1 * B.z + w_n2 * C.z;
                            xj[qq * 4 + 3] = w_n0 * A.w + w_n1 * B.w + w_n2 * C.w;
                        }
                    } else {
#pragma unroll
                        for (int cc = 0; cc < CPT; ++cc)
                            xj[cc] = w_n0 * sgA[0][cc] + w_n1 * sgA[1][cc] + w_n2 * sgA[2][cc];
                    }
                } else if (ap == 2) {
                    if (CROW == 128) {
                        const float4* p3 = (const float4*)(xb_ + (size_t)i_n3 * CROW + cs_n);
                        const float4* p4 = (const float4*)(xb_ + (size_t)i_n4 * CROW + cs_n);
                        const float4* p5 = (const float4*)(xb_ + (size_t)i_n5 * CROW + cs_n);
#pragma unroll
                        for (int qq = 0; qq < CPT / 4; ++qq) { qb0[qq] = p3[qq]; qb1[qq] = p4[qq]; qb2[qq] = p5[qq]; }
                    } else {
#pragma unroll
                        for (int cc = 0; cc < CPT; ++cc) {
                            int c = cs_n + cc;
                            bool ok = (c < CROW);
                            sgB[0][cc] = ok ? xb_[(size_t)i_n3 * CROW + c] : 0.f;
                            sgB[1][cc] = ok ? xb_[(size_t)i_n4 * CROW + c] : 0.f;
                            sgB[2][cc] = ok ? xb_[(size_t)i_n5 * CROW + c] : 0.f;
                        }
                    }
                } else if (ap == 3) {
                    if (CROW == 128) {
#pragma unroll
                        for (int qq = 0; qq < CPT / 4; ++qq) {
                            float4 D = qb0[qq], E = qb1[qq], F = qb2[qq];
                            xj4[qq * 4 + 0] = w_n3 * D.x + w_n4 * E.x + w_n5 * F.x;
                            xj4[qq * 4 + 1] = w_n3 * D.y + w_n4 * E.y + w_n5 * F.y;
                            xj4[qq * 4 + 2] = w_n3 * D.z + w_n4 * E.z + w_n5 * F.z;
                            xj4[qq * 4 + 3] = w_n3 * D.w + w_n4 * E.w + w_n5 * F.w;
                        }
                    } else {
#pragma unroll
                        for (int cc = 0; cc < CPT; ++cc)
                            xj4[cc] = w_n3 * sgB[0][cc] + w_n4 * sgB[1][cc] + w_n5 * sgB[2][cc];
                    }
                } else if (ap == 4) {
                    // prefetch idx/w for group g+2 (after last use of w_n)
                    if (gidx + 2 < G) {
                        const int rn = (gidx + 2) / CB;
                        const int gi1 = (vglob_b * RA + rn * 8 + jI) * 3;
                        const int gi2 = gi1 + 12;
                        i_n0 = idxb[gi1]; i_n1 = idxb[gi1 + 1]; i_n2 = idxb[gi1 + 2];
                        i_n3 = idxb[gi2]; i_n4 = idxb[gi2 + 1]; i_n5 = idxb[gi2 + 2];
                        w_n0 = wb[gi1]; w_n1 = wb[gi1 + 1]; w_n2 = wb[gi1 + 2];
                        w_n3 = wb[gi2]; w_n4 = wb[gi2 + 1]; w_n5 = wb[gi2 + 2];
                    }
                } else if (ap == 5) {
#pragma unroll
                    for (int cc = 0; cc < CPT; ++cc) {
                        float a_ = xj[cc], b_ = xj4[cc];
                        xj[cc] = a_ + b_;          // Ie
                        xj4[cc] = a_ - b_;         // Io
                    }
                } else if (ap == 6) {
                    store_split2(xj, ibuf ^ 1, jI, jI + 4, 0u);
                } else {
                    store_split2(xj4, ibuf ^ 1, 8 + jI, 12 + jI, 0x80008000u);
                }
            }
        }
        __syncthreads();
    }

    if (FUSE) {
        // reconstruct out[o]=Se'+So', out[o+4]=Se'-So'; elu+bias; AMP; BN
        float ssP[MT][2][4], ssM[MT][2][4];
#pragma unroll
        for (int mt = 0; mt < MT; ++mt)
#pragma unroll
            for (int mg = 0; mg < 2; ++mg)
#pragma unroll
                for (int r = 0; r < 4; ++r) { ssP[mt][mg][r] = 0.f; ssM[mt][mg][r] = 0.f; }
#pragma unroll
        for (int mt = 0; mt < MT; ++mt)
#pragma unroll
            for (int mg = 0; mg < 2; ++mg)
#pragma unroll
                for (int nj = 0; nj < NJF; ++nj)
#pragma unroll
                    for (int r = 0; r < 4; ++r) {
                        const int t = wn + nj * 16 + fr;
                        float se = acc[mt][mg][nj][r], so = acc[mt][mg + 2][nj][r];
                        float vP = elu_f(se + so + bias[t]);   // o = r
                        float vM = elu_f(se - so + bias[t]);   // o = r+4
                        acc[mt][mg][nj][r] = vP;
                        acc[mt][mg + 2][nj][r] = vM;
                        ssP[mt][mg][r] += vP * vP;
                        ssM[mt][mg][r] += vM * vM;
                    }
#pragma unroll
        for (int mt = 0; mt < MT; ++mt)
#pragma unroll
            for (int mg = 0; mg < 2; ++mg)
#pragma unroll
                for (int r = 0; r < 4; ++r) {
                    float s1 = ssP[mt][mg][r];
                    s1 += __shfl_xor(s1, 1); s1 += __shfl_xor(s1, 2);
                    s1 += __shfl_xor(s1, 4); s1 += __shfl_xor(s1, 8);
                    float s2 = ssM[mt][mg][r];
                    s2 += __shfl_xor(s2, 1); s2 += __shfl_xor(s2, 2);
                    s2 += __shfl_xor(s2, 4); s2 += __shfl_xor(s2, 8);
                    if (fr == 0) {
                        normp[(mt * 8 + mg * 4 + fq) * 8 + r][wid] = s1;
                        normp[(mt * 8 + mg * 4 + fq) * 8 + r + 4][wid] = s2;
                    }
                }
        __syncthreads();
        if (POOL && tid < T) poolmax[tid] = 0u;
        if (tid < 8 * MT) {
            float best = -1.f; int bsel = 0;
#pragma unroll
            for (int oo = 0; oo < 8; ++oo) {
                float tot = 0.f;
#pragma unroll
                for (int wq = 0; wq < NW; ++wq) tot += normp[tid * 8 + oo][wq];
                if (tot > best) { best = tot; bsel = oo; }   // first max wins
            }
            bo[tid] = bsel;
        }
        __syncthreads();
        const float rsbn = rsqrtf(1.001f);
#pragma unroll
        for (int mt = 0; mt < MT; ++mt)
#pragma unroll
            for (int mg = 0; mg < 2; ++mg)
#pragma unroll
                for (int r = 0; r < 4; ++r) {
                    const int vloc = mt * 8 + mg * 4 + fq;
                    const int bsel = bo[vloc];
                    if (r == bsel) {
                        const int vg = (m0 >> 3) + vloc;
#pragma unroll
                        for (int nj = 0; nj < NJF; ++nj) {
                            const int t = wn + nj * 16 + fr;
                            float f = acc[mt][mg][nj][r] * g[t] * rsbn + be[t];
                            if (!POOL) xout[(size_t)vg * T + t] = f;
                            else atomicMax(&poolmax[t], encf(f));
                        }
                    }
                    if (r + 4 == bsel) {
                        const int vg = (m0 >> 3) + vloc;
#pragma unroll
                        for (int nj = 0; nj < NJF; ++nj) {
                            const int t = wn + nj * 16 + fr;
                            float f = acc[mt][mg + 2][nj][r] * g[t] * rsbn + be[t];
                            if (!POOL) xout[(size_t)vg * T + t] = f;
                            else atomicMax(&poolmax[t], encf(f));
                        }
                    }
                }
        if (POOL) {
            __syncthreads();
            if (tid < T) {
                unsigned pv = poolmax[tid];
                if (pv) atomicMax((unsigned*)xout + (((size_t)b) << 8) + tid, pv);
            }
        }
    }
}

// Fused head: decode pooled max + 3-layer MLP. One block per batch.
__global__ __launch_bounds__(256) void head_k(const float* __restrict__ partial,
                                              const float* __restrict__ w1, const float* __restrict__ c1,
                                              const float* __restrict__ w2, const float* __restrict__ c2,
                                              const float* __restrict__ w3, const float* __restrict__ c3,
                                              float* __restrict__ outp) {
    __shared__ float p[256], h1s[512], h2s[256];
    const int b = blockIdx.x, tid = threadIdx.x;
    const unsigned* gp = (const unsigned*)partial;
    p[tid] = decf(gp[b * 256 + tid]);
    __syncthreads();
#pragma unroll
    for (int rep = 0; rep < 2; ++rep) {
        int n = rep * 256 + tid;
        float s = c1[n];
        for (int k = 0; k < 256; ++k) s += p[k] * w1[k * 512 + n];
        h1s[n] = elu_f(s);
    }
    __syncthreads();
    {
        float s = c2[tid];
        for (int k = 0; k < 512; ++k) s += h1s[k] * w2[k * 256 + tid];
        h2s[tid] = elu_f(s);
    }
    __syncthreads();
    if (tid < 40) {
        float s = c3[tid];
        for (int k = 0; k < 256; ++k) s += h2s[k] * w3[k * 40 + tid];
        outp[b * 40 + tid] = s;
    }
}

extern "C" void kernel_launch(void* const* d_in, const int* in_sizes, int n_in,
                              void* d_out, int out_size, void* d_ws, size_t ws_size,
                              hipStream_t stream) {
    const float* signal = (const float*)d_in[0];
    const int* bc_idx = (const int*)d_in[1];
    const float* bc_w = (const float*)d_in[2];
    const float* k0 = (const float*)d_in[3];
    const float* b0 = (const float*)d_in[4];
    const float* g0 = (const float*)d_in[5];
    const float* be0 = (const float*)d_in[6];
    const float* k1 = (const float*)d_in[7];
    const float* b1 = (const float*)d_in[8];
    const float* g1 = (const float*)d_in[9];
    const float* be1 = (const float*)d_in[10];
    const float* k2 = (const float*)d_in[11];
    const float* b2 = (const float*)d_in[12];
    const float* g2 = (const float*)d_in[13];
    const float* be2 = (const float*)d_in[14];
    const float* w1 = (const float*)d_in[15];
    const float* c1 = (const float*)d_in[16];
    const float* w2 = (const float*)d_in[17];
    const float* c2 = (const float*)d_in[18];
    const float* w3 = (const float*)d_in[19];
    const float* c3 = (const float*)d_in[20];
    float* outp = (float*)d_out;

    // Workspace layout: xa 4MB | xb 4MB | gpool 16KB | wt0 0.66MB | wt1 2.62MB | wt2 5.24MB
    float* ws = (float*)d_ws;
    float* xa = ws;                                        // [8192][<=128] f32
    float* xb = xa + (size_t)8192 * 128;
    unsigned* gpool = (unsigned*)(xb + (size_t)8192 * 128); // [4][256] enc-u32
    unsigned short* wt0 = (unsigned short*)(gpool + 4096);
    unsigned short* wt1 = wt0 + (size_t)40 * 2 * 128 * 32;
    unsigned short* wt2 = wt1 + (size_t)160 * 2 * 128 * 32;

    // 1. prep: norm -> xa, expand (parity-transformed) weights, zero gpool
    prep_k<<<9284, 256, 0, stream>>>(signal, xa, k0, wt0, k1, wt1, k2, wt2, gpool);

    // ---- layer 0: CROW=30 (KB=40), T=128, NW=2, MT=1 (NJF=4), fused AMP ----
    conv_k<30, 128, 40, 2, 1, true, false><<<dim3(1, 1024), 128, 0, stream>>>(
        xa, bc_idx, bc_w, wt0, b0, g0, be0, xb);

    // ---- layer 1: CROW=128 (KB=160), T=128, NW=2, MT=1 (NJF=4), fused AMP ----
    conv_k<128, 128, 160, 2, 1, true, false><<<dim3(1, 1024), 128, 0, stream>>>(
        xb, bc_idx, bc_w, wt1, b1, g1, be1, xa);

    // ---- layer 2: CROW=128 (KB=160), T=256, NW=8 (512 thr), MT=2 (BM=128, NJF=2),
    //      fused AMP+POOL: 8 waves x (128x32) wave-tiles, acc=64 AGPR, no spill ----
    conv_k<128, 256, 160, 8, 2, true, true><<<dim3(1, 512), 512, 0, stream>>>(
        xa, bc_idx, bc_w, wt2, b2, g2, be2, (float*)gpool);

    // ---- fused MLP head (decodes pooled max) ----
    head_k<<<Bz, 256, 0, stream>>>((const float*)gpool, w1, c1, w2, c2, w3, c3, outp);
}

// Round 13
// 584.099 us; speedup vs baseline: 1.3444x; 1.3078x over previous
//
#include <hip/hip_runtime.h>
#include <hip/hip_bf16.h>
#include <math.h>

// Problem constants
#define Bz 4
#define Vz 2048
#define RA 40   // R*A = 5*8

typedef short bf16x8 __attribute__((ext_vector_type(8)));
typedef float f32x4 __attribute__((ext_vector_type(4)));

__device__ __forceinline__ unsigned fasu(float f){ union{float f;unsigned u;}x;x.f=f;return x.u; }
__device__ __forceinline__ float usaf(unsigned u){ union{unsigned u;float f;}x;x.u=u;return x.f; }

// fp32 -> bf16 RNE (weight split, done once per layer)
__device__ __forceinline__ unsigned short f2bf(float f) {
    unsigned u = fasu(f);
    unsigned r = u + 0x7FFF + ((u >> 16) & 1);
    return (unsigned short)(r >> 16);
}
__device__ __forceinline__ float bf2f(unsigned short h) { return usaf(((unsigned)h) << 16); }

__constant__ float NORM_MEAN_C[30] = {
    -3.7189561e-06f, 0.000286194f, 0.0020740835f, 6.5275993f, -0.0052857199f,
    10.554636f, 0.057773598f, 13.915789f, 0.060970016f, 16.840271f,
    0.0570364f, 19.415283f, 0.044104282f, 21.721455f, 0.11490919f,
    23.64683f, 0.099816084f, 25.365578f, 0.01769533f, 26.861437f,
    0.054662503f, 28.197876f, -0.0024771576f, 29.295244f, 0.039666731f,
    30.319246f, 0.0088442909f, 31.160933f, -0.026727753f, 31.874565f};
__constant__ float NORM_VAR_C[30] = {
    3.3091978e-06f, 0.00016750646f, 0.80988622f, 85135.219f, 1.5621265f,
    222580.2f, 8.812871f, 386912.78f, 10.180468f, 566622.44f,
    9.8600769f, 753158.06f, 7.8372045f, 942701.62f, 30.926426f,
    1117233.0f, 25.045353f, 1285543.9f, 6.3646226f, 1441639.1f,
    12.326629f, 1588653.4f, 6.9686499f, 1714707.9f, 10.755516f,
    1836677.8f, 8.416419f, 1940088.8f, 10.344138f, 2029969.6f};

__device__ __forceinline__ float elu_f(float x) {
    return x > 0.f ? x : expm1f(x);
}

// order-preserving float->uint map (uint max == float max, bit-exact)
__device__ __forceinline__ unsigned encf(float f) {
    unsigned u = fasu(f);
    return (f < 0.f) ? ~u : (u | 0x80000000u);
}
__device__ __forceinline__ float decf(unsigned u) {
    return (u & 0x80000000u) ? usaf(u & 0x7FFFFFFFu) : usaf(~u);
}

// Weight expand, parity-transformed: kb = ((r*CB + cblk)*4 + j)*2 + p,
// p=0 -> Ks[j]/2 = (K[r,j]+K[r,j+4])/2 ; p=1 -> Kd[j]/2 = (K[r,j]-K[r,j+4])/2.
// Split-bf16, fragment-linear within kb: off = (n>>4)*512 + (kk>>3)*128 +
// (n&15)*8 + (kk&7); lo plane at +T*32.
template <int CROW, int T, int KB>
__device__ __forceinline__ void expand_body(int e, const float* __restrict__ kern,
                                            unsigned short* __restrict__ wt) {
    constexpr int CB = (CROW == 128) ? 4 : 1;
    int kb = e / (T * 32);
    int rem = e % (T * 32);
    int n = rem >> 5, kk = rem & 31;
    int par = kb & 1;
    int jp = (kb >> 1) & 3;
    int g = kb >> 3;                 // = r*CB + cblk
    int cblk = g % CB;
    int r = g / CB;
    int c = cblk * 32 + kk;
    float v = 0.f;
    if (c < CROW) {
        float k1 = kern[((size_t)((r * 8 + jp) * T + n)) * CROW + c];
        float k2 = kern[((size_t)((r * 8 + jp + 4) * T + n)) * CROW + c];
        v = 0.5f * (par == 0 ? (k1 + k2) : (k1 - k2));
    }
    unsigned short hi = f2bf(v);
    unsigned short lo = f2bf(v - bf2f(hi));
    size_t off = ((size_t)kb * 2) * T * 32 + (n >> 4) * 512 + (kk >> 3) * 128 + (n & 15) * 8 + (kk & 7);
    wt[off] = hi;
    wt[off + (size_t)T * 32] = lo;
}

// One prep dispatch: norm + 3x expand + pool-buffer zero (region-dispatch).
__global__ void prep_k(const float* __restrict__ sig, float* __restrict__ x0,
                       const float* __restrict__ k0, unsigned short* __restrict__ wt0,
                       const float* __restrict__ k1, unsigned short* __restrict__ wt1,
                       const float* __restrict__ k2, unsigned short* __restrict__ wt2,
                       unsigned* __restrict__ gpool) {
    const int bid = blockIdx.x, tid = threadIdx.x;
    if (bid < 960) {
        int e = bid * 256 + tid;
        if (e < Bz * Vz * 30) {
            int c = e % 30;
            x0[e] = (sig[e] - NORM_MEAN_C[c]) * rsqrtf(NORM_VAR_C[c]);
        }
    } else if (bid < 1600) {
        int e = (bid - 960) * 256 + tid;
        if (e < 40 * 128 * 32) expand_body<30, 128, 40>(e, k0, wt0);
    } else if (bid < 4160) {
        int e = (bid - 1600) * 256 + tid;
        if (e < 160 * 128 * 32) expand_body<128, 128, 160>(e, k1, wt1);
    } else if (bid < 9280) {
        int e = (bid - 4160) * 256 + tid;
        if (e < 160 * 256 * 32) expand_body<128, 256, 160>(e, k2, wt2);
    } else {
        int e = (bid - 9280) * 256 + tid;
        if (e < Bz * 256) gpool[e] = 0u;
    }
}

// Fused conv GEMM, R8 (proven best): radix-2 parity decomposition of the
// length-8 angular circular correlation. out[o]+out[o+4] = sum_j
// Ie[(j+o)&3]*Ks[j] (circular-4); out[o]-out[o+4] = sum_j IoExt[(j+o)&7]*Kd[j]
// (negacyclic-4 via antiperiodic doubled storage IoExt[s]=Io[s] s<4,
// -Io[s-4] s>=4). HALVES MFMA count vs direct: M-tile = 8v x {4 even + 4 odd
// rows}; each of 8 steps/group fires only its parity's 2 m-frags. Weights
// carry the 1/2 (wt = Ks/2, Kd/2); epilogue: out[o]=Se'+So',
// out[o+4]=Se'-So'. A-LDS: 16 slots/vertex (IeExt 8 + IoExt 8), slot
// swizzled by +2*(v&3). Sign-flip-by-XOR on split-bf16 planes is bit-exact.
// Schedule (R3-derived): per 8-ap group, gathers for g+1 at ap0/1, idx
// prefetch at ap2, interp at ap3/4, butterfly ap5, stores ap6/7; ONE barrier
// per group; s_setprio around each MFMA cluster. VGPR pinned <=128 + 64 AGPR.
// R12 lesson: layer-2 grid is dim3(1,1024) (BM=64, 65536 rows) — the failed
// revert carried R11's dim3(1,512), leaving batches 2-3 unprocessed (gpool
// stayed 0 -> decf(0)=NaN). Grid restored here; kernel code is R8-identical.
// Epilogue: elu+bias, AMP argmax over 8 rotations, BN, write or fused pool.
template <int CROW, int T, int KB, int NW, bool FUSE, bool POOL>
__global__ __launch_bounds__(64 * NW) void conv_k(const float* __restrict__ x,
                                              const int* __restrict__ bc_idx,
                                              const float* __restrict__ bc_w,
                                              const unsigned short* __restrict__ wt,
                                              const float* __restrict__ bias,
                                              const float* __restrict__ g,
                                              const float* __restrict__ be,
                                              float* __restrict__ xout) {
    constexpr int CB = (CROW == 128) ? 4 : 1;   // c-blocks per r
    constexpr int G = KB / 8;                   // (r,cblk) groups
    constexpr int CW = 2 * NW;                  // c-chunks per (v,j) build unit
    constexpr int CPT = 32 / CW;                // c-elements per thread (8 or 4)
    __shared__ unsigned short Ih[2][4096], Il[2][4096];
    __shared__ float normp[64][NW];
    __shared__ int bo[8];
    __shared__ unsigned poolmax[64 * NW];
    const int tid = threadIdx.x;
    const int wid = tid >> 6, lane = tid & 63;
    const int fr = lane & 15, fq = lane >> 4;
    const int fr2 = fr >> 2, om_l = fr & 3;
    const int wn = wid * 64;                      // column-wave offset
    const int m0 = blockIdx.y * 64;
    const int b = m0 >> 14;                       // batch
    const float* xb_ = x + (size_t)b * Vz * CROW;
    const int* idxb = bc_idx + (size_t)b * Vz * RA * 3;
    const float* wb = bc_w + (size_t)b * Vz * RA * 3;

    // I-build decomposition: thread = (vertex vbI, pair-index jI, c-chunk cidx)
    const int cidx = tid % CW;
    const int jI = (tid / CW) & 3;
    const int vbI = tid / (CW * 4);               // 0..7
    const int vglob_b = ((m0 & 16383) >> 3) + vbI;
    const int wbase = vbI * 512 + ((cidx * CPT) >> 3) * 128 + ((cidx * CPT) & 7);
    const int nbase = wn >> 4;

    f32x4 acc[4][4] = {};   // mi: 0,1 = even-part (vgrp 0,1); 2,3 = odd-part

    // pack split-bf16 and write to two slots (second optionally negated)
    auto store_split2 = [&](const float* vv, int buf, int sA, int sB, unsigned sgB) {
        unsigned hp[CPT / 2], lp[CPT / 2];
#pragma unroll
        for (int p2 = 0; p2 < CPT / 2; ++p2) {
            float v0 = vv[2 * p2], v1 = vv[2 * p2 + 1];
            unsigned u0 = fasu(v0), u1 = fasu(v1);
            unsigned h0 = u0 & 0xFFFF0000u, h1 = u1 & 0xFFFF0000u;
            float l0 = v0 - usaf(h0), l1 = v1 - usaf(h1);
            hp[p2] = (u0 >> 16) | h1;
            lp[p2] = (fasu(l0) >> 16) | (fasu(l1) & 0xFFFF0000u);
        }
        auto put = [&](int slot, unsigned sg) {
            const int sl = (slot & 8) | (((slot & 7) + 2 * (vbI & 3)) & 7);
            const int ad = wbase + sl * 8;
            if constexpr (CPT == 8) {
                *(uint4*)&Ih[buf][ad] = make_uint4(hp[0] ^ sg, hp[1] ^ sg, hp[2] ^ sg, hp[3] ^ sg);
                *(uint4*)&Il[buf][ad] = make_uint4(lp[0] ^ sg, lp[1] ^ sg, lp[2] ^ sg, lp[3] ^ sg);
            } else {
                *(uint2*)&Ih[buf][ad] = make_uint2(hp[0] ^ sg, hp[1] ^ sg);
                *(uint2*)&Il[buf][ad] = make_uint2(lp[0] ^ sg, lp[1] ^ sg);
            }
        };
        put(sA, 0u);
        put(sB, sgB);
    };

    // ---- prologue: build tile for group 0 (r=0,cblk=0); prefetch idx/w g=1 ----
    int i_n0 = 0, i_n1 = 0, i_n2 = 0, i_n3 = 0, i_n4 = 0, i_n5 = 0;
    float w_n0 = 0.f, w_n1 = 0.f, w_n2 = 0.f, w_n3 = 0.f, w_n4 = 0.f, w_n5 = 0.f;
    {
        const int gi1 = (vglob_b * RA + jI) * 3;
        const int gi2 = gi1 + 12;                 // (ra+4)*3
        int a0 = idxb[gi1], a1 = idxb[gi1 + 1], a2 = idxb[gi1 + 2];
        int a3 = idxb[gi2], a4 = idxb[gi2 + 1], a5 = idxb[gi2 + 2];
        float u0 = wb[gi1], u1 = wb[gi1 + 1], u2 = wb[gi1 + 2];
        float u3 = wb[gi2], u4 = wb[gi2 + 1], u5 = wb[gi2 + 2];
        float xj[CPT], xj4[CPT];
        const int cs0 = cidx * CPT;
        if (CROW == 128) {
            const float4* p0 = (const float4*)(xb_ + (size_t)a0 * CROW + cs0);
            const float4* p1 = (const float4*)(xb_ + (size_t)a1 * CROW + cs0);
            const float4* p2 = (const float4*)(xb_ + (size_t)a2 * CROW + cs0);
            const float4* p3 = (const float4*)(xb_ + (size_t)a3 * CROW + cs0);
            const float4* p4 = (const float4*)(xb_ + (size_t)a4 * CROW + cs0);
            const float4* p5 = (const float4*)(xb_ + (size_t)a5 * CROW + cs0);
#pragma unroll
            for (int qq = 0; qq < CPT / 4; ++qq) {
                float4 A = p0[qq], B = p1[qq], C = p2[qq];
                xj[qq * 4 + 0] = u0 * A.x + u1 * B.x + u2 * C.x;
                xj[qq * 4 + 1] = u0 * A.y + u1 * B.y + u2 * C.y;
                xj[qq * 4 + 2] = u0 * A.z + u1 * B.z + u2 * C.z;
                xj[qq * 4 + 3] = u0 * A.w + u1 * B.w + u2 * C.w;
                float4 D = p3[qq], E = p4[qq], F = p5[qq];
                xj4[qq * 4 + 0] = u3 * D.x + u4 * E.x + u5 * F.x;
                xj4[qq * 4 + 1] = u3 * D.y + u4 * E.y + u5 * F.y;
                xj4[qq * 4 + 2] = u3 * D.z + u4 * E.z + u5 * F.z;
                xj4[qq * 4 + 3] = u3 * D.w + u4 * E.w + u5 * F.w;
            }
        } else {
#pragma unroll
            for (int cc = 0; cc < CPT; ++cc) {
                int c = cs0 + cc;
                bool ok = (c < CROW);
                xj[cc] = ok ? (u0 * xb_[(size_t)a0 * CROW + c] + u1 * xb_[(size_t)a1 * CROW + c] + u2 * xb_[(size_t)a2 * CROW + c]) : 0.f;
                xj4[cc] = ok ? (u3 * xb_[(size_t)a3 * CROW + c] + u4 * xb_[(size_t)a4 * CROW + c] + u5 * xb_[(size_t)a5 * CROW + c]) : 0.f;
            }
        }
#pragma unroll
        for (int cc = 0; cc < CPT; ++cc) {
            float a_ = xj[cc], b_ = xj4[cc];
            xj[cc] = a_ + b_;                      // Ie
            xj4[cc] = a_ - b_;                     // Io
        }
        store_split2(xj, 0, jI, jI + 4, 0u);
        store_split2(xj4, 0, 8 + jI, 12 + jI, 0x80008000u);
        if (G > 1) {
            const int rn = 1 / CB;
            const int gi1n = (vglob_b * RA + rn * 8 + jI) * 3;
            const int gi2n = gi1n + 12;
            i_n0 = idxb[gi1n]; i_n1 = idxb[gi1n + 1]; i_n2 = idxb[gi1n + 2];
            i_n3 = idxb[gi2n]; i_n4 = idxb[gi2n + 1]; i_n5 = idxb[gi2n + 2];
            w_n0 = wb[gi1n]; w_n1 = wb[gi1n + 1]; w_n2 = wb[gi1n + 2];
            w_n3 = wb[gi2n]; w_n4 = wb[gi2n + 1]; w_n5 = wb[gi2n + 2];
        }
    }
    __syncthreads();

    for (int gidx = 0; gidx < G; ++gidx) {
        const bool hn = (gidx + 1 < G);
        // save idx/w for building group g+1 (prefetch for g+2 overwrites)
        const int ni0 = i_n0, ni1 = i_n1, ni2 = i_n2, ni3 = i_n3, ni4 = i_n4, ni5 = i_n5;
        const float mw0 = w_n0, mw1 = w_n1, mw2 = w_n2, mw3 = w_n3, mw4 = w_n4, mw5 = w_n5;
        const int bgn = gidx + 1;
        const int cs_n = (bgn % CB) * 32 + cidx * CPT;
        const int ibuf = gidx & 1;
        float4 qa0[CPT / 4], qa1[CPT / 4], qa2[CPT / 4];
        float4 qb0[CPT / 4], qb1[CPT / 4], qb2[CPT / 4];
        float sg[6][CPT];                          // CROW==30 scalar path
        float xj[CPT], xj4[CPT];
#pragma unroll
        for (int ap = 0; ap < 8; ++ap) {
            const int jp = ap >> 1, par = ap & 1;
            // ---- B fragment loads (Ks/2 for par=0, Kd/2 for par=1) ----
            const int kb = gidx * 8 + ap;
            const unsigned short* bb = wt + ((size_t)kb * 2) * (T * 32) +
                                       (size_t)nbase * 512 + lane * 8;
            bf16x8 bh[4], bl[4];
#pragma unroll
            for (int nj = 0; nj < 4; ++nj) {
                bh[nj] = *(const bf16x8*)(bb + nj * 512);
                bl[nj] = *(const bf16x8*)(bb + (size_t)T * 32 + nj * 512);
            }
            // ---- A fragments: slot (par, (jp+om)&7), swizzled; 2 m-frags ----
            const int sp = (jp + om_l + 2 * fr2) & 7;   // slot low3 after swizzle
            const int sl = par * 8 + sp;
            bf16x8 ah[2], al[2];
#pragma unroll
            for (int miq = 0; miq < 2; ++miq) {
                const int ad = (miq * 4 + fr2) * 512 + fq * 128 + sl * 8;
                ah[miq] = *(const bf16x8*)&Ih[ibuf][ad];
                al[miq] = *(const bf16x8*)&Il[ibuf][ad];
            }
            __builtin_amdgcn_s_setprio(1);
#pragma unroll
            for (int miq = 0; miq < 2; ++miq)
#pragma unroll
                for (int nj = 0; nj < 4; ++nj) {
                    const int mi = par * 2 + miq;
                    acc[mi][nj] = __builtin_amdgcn_mfma_f32_16x16x32_bf16(ah[miq], bh[nj], acc[mi][nj], 0, 0, 0);
                    acc[mi][nj] = __builtin_amdgcn_mfma_f32_16x16x32_bf16(ah[miq], bl[nj], acc[mi][nj], 0, 0, 0);
                    acc[mi][nj] = __builtin_amdgcn_mfma_f32_16x16x32_bf16(al[miq], bh[nj], acc[mi][nj], 0, 0, 0);
                }
            __builtin_amdgcn_s_setprio(0);
            // ---- interleaved I-build task for group g+1 ----
            if (hn) {
                if (ap == 0) {
                    if (CROW == 128) {
                        const float4* p0 = (const float4*)(xb_ + (size_t)ni0 * CROW + cs_n);
                        const float4* p1 = (const float4*)(xb_ + (size_t)ni1 * CROW + cs_n);
                        const float4* p2 = (const float4*)(xb_ + (size_t)ni2 * CROW + cs_n);
#pragma unroll
                        for (int qq = 0; qq < CPT / 4; ++qq) { qa0[qq] = p0[qq]; qa1[qq] = p1[qq]; qa2[qq] = p2[qq]; }
                    } else {
#pragma unroll
                        for (int cc = 0; cc < CPT; ++cc) {
                            int c = cs_n + cc;
                            bool ok = (c < CROW);
                            sg[0][cc] = ok ? xb_[(size_t)ni0 * CROW + c] : 0.f;
                            sg[1][cc] = ok ? xb_[(size_t)ni1 * CROW + c] : 0.f;
                            sg[2][cc] = ok ? xb_[(size_t)ni2 * CROW + c] : 0.f;
                        }
                    }
                } else if (ap == 1) {
                    if (CROW == 128) {
                        const float4* p3 = (const float4*)(xb_ + (size_t)ni3 * CROW + cs_n);
                        const float4* p4 = (const float4*)(xb_ + (size_t)ni4 * CROW + cs_n);
                        const float4* p5 = (const float4*)(xb_ + (size_t)ni5 * CROW + cs_n);
#pragma unroll
                        for (int qq = 0; qq < CPT / 4; ++qq) { qb0[qq] = p3[qq]; qb1[qq] = p4[qq]; qb2[qq] = p5[qq]; }
                    } else {
#pragma unroll
                        for (int cc = 0; cc < CPT; ++cc) {
                            int c = cs_n + cc;
                            bool ok = (c < CROW);
                            sg[3][cc] = ok ? xb_[(size_t)ni3 * CROW + c] : 0.f;
                            sg[4][cc] = ok ? xb_[(size_t)ni4 * CROW + c] : 0.f;
                            sg[5][cc] = ok ? xb_[(size_t)ni5 * CROW + c] : 0.f;
                        }
                    }
                } else if (ap == 2) {
                    if (gidx + 2 < G) {
                        const int rn = (gidx + 2) / CB;
                        const int gi1 = (vglob_b * RA + rn * 8 + jI) * 3;
                        const int gi2 = gi1 + 12;
                        i_n0 = idxb[gi1]; i_n1 = idxb[gi1 + 1]; i_n2 = idxb[gi1 + 2];
                        i_n3 = idxb[gi2]; i_n4 = idxb[gi2 + 1]; i_n5 = idxb[gi2 + 2];
                        w_n0 = wb[gi1]; w_n1 = wb[gi1 + 1]; w_n2 = wb[gi1 + 2];
                        w_n3 = wb[gi2]; w_n4 = wb[gi2 + 1]; w_n5 = wb[gi2 + 2];
                    }
                } else if (ap == 3) {
                    if (CROW == 128) {
#pragma unroll
                        for (int qq = 0; qq < CPT / 4; ++qq) {
                            float4 A = qa0[qq], B = qa1[qq], C = qa2[qq];
                            xj[qq * 4 + 0] = mw0 * A.x + mw1 * B.x + mw2 * C.x;
                            xj[qq * 4 + 1] = mw0 * A.y + mw1 * B.y + mw2 * C.y;
                            xj[qq * 4 + 2] = mw0 * A.z + mw1 * B.z + mw2 * C.z;
                            xj[qq * 4 + 3] = mw0 * A.w + mw1 * B.w + mw2 * C.w;
                        }
                    } else {
#pragma unroll
                        for (int cc = 0; cc < CPT; ++cc)
                            xj[cc] = mw0 * sg[0][cc] + mw1 * sg[1][cc] + mw2 * sg[2][cc];
                    }
                } else if (ap == 4) {
                    if (CROW == 128) {
#pragma unroll
                        for (int qq = 0; qq < CPT / 4; ++qq) {
                            float4 D = qb0[qq], E = qb1[qq], F = qb2[qq];
                            xj4[qq * 4 + 0] = mw3 * D.x + mw4 * E.x + mw5 * F.x;
                            xj4[qq * 4 + 1] = mw3 * D.y + mw4 * E.y + mw5 * F.y;
                            xj4[qq * 4 + 2] = mw3 * D.z + mw4 * E.z + mw5 * F.z;
                            xj4[qq * 4 + 3] = mw3 * D.w + mw4 * E.w + mw5 * F.w;
                        }
                    } else {
#pragma unroll
                        for (int cc = 0; cc < CPT; ++cc)
                            xj4[cc] = mw3 * sg[3][cc] + mw4 * sg[4][cc] + mw5 * sg[5][cc];
                    }
                } else if (ap == 5) {
#pragma unroll
                    for (int cc = 0; cc < CPT; ++cc) {
                        float a_ = xj[cc], b_ = xj4[cc];
                        xj[cc] = a_ + b_;          // Ie
                        xj4[cc] = a_ - b_;         // Io
                    }
                } else if (ap == 6) {
                    store_split2(xj, ibuf ^ 1, jI, jI + 4, 0u);
                } else {
                    store_split2(xj4, ibuf ^ 1, 8 + jI, 12 + jI, 0x80008000u);
                }
            }
        }
        __syncthreads();
    }

    if (FUSE) {
        // reconstruct out[o]=Se'+So', out[o+4]=Se'-So'; elu+bias; AMP; BN
        float ssP[2][4], ssM[2][4];
#pragma unroll
        for (int mg = 0; mg < 2; ++mg)
#pragma unroll
            for (int r = 0; r < 4; ++r) { ssP[mg][r] = 0.f; ssM[mg][r] = 0.f; }
#pragma unroll
        for (int mg = 0; mg < 2; ++mg)
#pragma unroll
            for (int nj = 0; nj < 4; ++nj)
#pragma unroll
                for (int r = 0; r < 4; ++r) {
                    const int t = wn + nj * 16 + fr;
                    float se = acc[mg][nj][r], so = acc[mg + 2][nj][r];
                    float vP = elu_f(se + so + bias[t]);   // o = r
                    float vM = elu_f(se - so + bias[t]);   // o = r+4
                    acc[mg][nj][r] = vP;
                    acc[mg + 2][nj][r] = vM;
                    ssP[mg][r] += vP * vP;
                    ssM[mg][r] += vM * vM;
                }
#pragma unroll
        for (int mg = 0; mg < 2; ++mg)
#pragma unroll
            for (int r = 0; r < 4; ++r) {
                float s1 = ssP[mg][r];
                s1 += __shfl_xor(s1, 1); s1 += __shfl_xor(s1, 2);
                s1 += __shfl_xor(s1, 4); s1 += __shfl_xor(s1, 8);
                float s2 = ssM[mg][r];
                s2 += __shfl_xor(s2, 1); s2 += __shfl_xor(s2, 2);
                s2 += __shfl_xor(s2, 4); s2 += __shfl_xor(s2, 8);
                if (fr == 0) {
                    normp[(mg * 4 + fq) * 8 + r][wid] = s1;
                    normp[(mg * 4 + fq) * 8 + r + 4][wid] = s2;
                }
            }
        __syncthreads();
        if (POOL) poolmax[tid] = 0u;
        if (tid < 8) {
            float best = -1.f; int bsel = 0;
#pragma unroll
            for (int oo = 0; oo < 8; ++oo) {
                float tot = 0.f;
#pragma unroll
                for (int wq = 0; wq < NW; ++wq) tot += normp[tid * 8 + oo][wq];
                if (tot > best) { best = tot; bsel = oo; }   // first max wins
            }
            bo[tid] = bsel;
        }
        __syncthreads();
        const float rsbn = rsqrtf(1.001f);
#pragma unroll
        for (int mg = 0; mg < 2; ++mg)
#pragma unroll
            for (int r = 0; r < 4; ++r) {
                const int vloc = mg * 4 + fq;
                const int bsel = bo[vloc];
                if (r == bsel) {
                    const int vg = (m0 >> 3) + vloc;
#pragma unroll
                    for (int nj = 0; nj < 4; ++nj) {
                        const int t = wn + nj * 16 + fr;
                        float f = acc[mg][nj][r] * g[t] * rsbn + be[t];
                        if (!POOL) xout[(size_t)vg * T + t] = f;
                        else atomicMax(&poolmax[t], encf(f));
                    }
                }
                if (r + 4 == bsel) {
                    const int vg = (m0 >> 3) + vloc;
#pragma unroll
                    for (int nj = 0; nj < 4; ++nj) {
                        const int t = wn + nj * 16 + fr;
                        float f = acc[mg + 2][nj][r] * g[t] * rsbn + be[t];
                        if (!POOL) xout[(size_t)vg * T + t] = f;
                        else atomicMax(&poolmax[t], encf(f));
                    }
                }
            }
        if (POOL) {
            __syncthreads();
            unsigned pv = poolmax[tid];
            if (pv) atomicMax((unsigned*)xout + (((size_t)b) << 8) + tid, pv);
        }
    }
}

// Fused head: decode pooled max + 3-layer MLP. One block per batch.
__global__ __launch_bounds__(256) void head_k(const float* __restrict__ partial,
                                              const float* __restrict__ w1, const float* __restrict__ c1,
                                              const float* __restrict__ w2, const float* __restrict__ c2,
                                              const float* __restrict__ w3, const float* __restrict__ c3,
                                              float* __restrict__ outp) {
    __shared__ float p[256], h1s[512], h2s[256];
    const int b = blockIdx.x, tid = threadIdx.x;
    const unsigned* gp = (const unsigned*)partial;
    p[tid] = decf(gp[b * 256 + tid]);
    __syncthreads();
#pragma unroll
    for (int rep = 0; rep < 2; ++rep) {
        int n = rep * 256 + tid;
        float s = c1[n];
        for (int k = 0; k < 256; ++k) s += p[k] * w1[k * 512 + n];
        h1s[n] = elu_f(s);
    }
    __syncthreads();
    {
        float s = c2[tid];
        for (int k = 0; k < 512; ++k) s += h1s[k] * w2[k * 256 + tid];
        h2s[tid] = elu_f(s);
    }
    __syncthreads();
    if (tid < 40) {
        float s = c3[tid];
        for (int k = 0; k < 256; ++k) s += h2s[k] * w3[k * 40 + tid];
        outp[b * 40 + tid] = s;
    }
}

extern "C" void kernel_launch(void* const* d_in, const int* in_sizes, int n_in,
                              void* d_out, int out_size, void* d_ws, size_t ws_size,
                              hipStream_t stream) {
    const float* signal = (const float*)d_in[0];
    const int* bc_idx = (const int*)d_in[1];
    const float* bc_w = (const float*)d_in[2];
    const float* k0 = (const float*)d_in[3];
    const float* b0 = (const float*)d_in[4];
    const float* g0 = (const float*)d_in[5];
    const float* be0 = (const float*)d_in[6];
    const float* k1 = (const float*)d_in[7];
    const float* b1 = (const float*)d_in[8];
    const float* g1 = (const float*)d_in[9];
    const float* be1 = (const float*)d_in[10];
    const float* k2 = (const float*)d_in[11];
    const float* b2 = (const float*)d_in[12];
    const float* g2 = (const float*)d_in[13];
    const float* be2 = (const float*)d_in[14];
    const float* w1 = (const float*)d_in[15];
    const float* c1 = (const float*)d_in[16];
    const float* w2 = (const float*)d_in[17];
    const float* c2 = (const float*)d_in[18];
    const float* w3 = (const float*)d_in[19];
    const float* c3 = (const float*)d_in[20];
    float* outp = (float*)d_out;

    // Workspace layout: xa 4MB | xb 4MB | gpool 16KB | wt0 0.66MB | wt1 2.62MB | wt2 5.24MB
    float* ws = (float*)d_ws;
    float* xa = ws;                                        // [8192][<=128] f32
    float* xb = xa + (size_t)8192 * 128;
    unsigned* gpool = (unsigned*)(xb + (size_t)8192 * 128); // [4][256] enc-u32
    unsigned short* wt0 = (unsigned short*)(gpool + 4096);
    unsigned short* wt1 = wt0 + (size_t)40 * 2 * 128 * 32;
    unsigned short* wt2 = wt1 + (size_t)160 * 2 * 128 * 32;

    // 1. prep: norm -> xa, expand (parity-transformed) weights, zero gpool
    prep_k<<<9284, 256, 0, stream>>>(signal, xa, k0, wt0, k1, wt1, k2, wt2, gpool);

    // ---- layer 0: CROW=30 (KB=40), T=128, NW=2 (128 thr, BM=64), fused AMP ----
    conv_k<30, 128, 40, 2, true, false><<<dim3(1, 1024), 128, 0, stream>>>(
        xa, bc_idx, bc_w, wt0, b0, g0, be0, xb);

    // ---- layer 1: CROW=128 (KB=160), T=128, NW=2 (128 thr, BM=64), fused AMP ----
    conv_k<128, 128, 160, 2, true, false><<<dim3(1, 1024), 128, 0, stream>>>(
        xb, bc_idx, bc_w, wt1, b1, g1, be1, xa);

    // ---- layer 2: CROW=128 (KB=160), T=256, NW=4 (256 thr, BM=64), fused AMP+POOL ----
    conv_k<128, 256, 160, 4, true, true><<<dim3(1, 1024), 256, 0, stream>>>(
        xa, bc_idx, bc_w, wt2, b2, g2, be2, (float*)gpool);

    // ---- fused MLP head (decodes pooled max) ----
    head_k<<<Bz, 256, 0, stream>>>((const float*)gpool, w1, c1, w2, c2, w3, c3, outp);
}